// Round 12
// baseline (1414.164 us; speedup 1.0000x reference)
//
#include <hip/hip_runtime.h>
#include <math.h>

// GRU-RCN bf16 MFMA, round-12: NF=2 (32 out-ch per wave, 2x MFMA per LDS read)
// + full-width row staging (one 66px row shared by both x-halves).
// B=8,T=16,C=Oh=64,HxW=56x56, 3x3 SAME.
// Per step t:
//   convUW: blocks<224 convU(t) -> z, r*h ; blocks>=224 convW(t+1) -> wx ring
//   convCX: blocks<112 convC(t) -> h', out ; blocks>=112 xprep(t+2)
// Wave layout in conv blocks: wv -> (chslice = wv&1 [32ch], xhalf = wv>>1).
// Layouts:
//   padded imgs (xpad[2]/hpad/rhpad): bf16 [b][58][66][64ci], 16B ci-slices
//     XOR-swizzled by (col&7) -> conflict-free ds_read_b128.
//   wcat: bf16 [plane(ky*3+kx)][o][ci] (W:192, U:128, C:64)
//   wx[2]: bf16 [b][y56][px64][192]; zbuf/hstate: fp16 [b][y][px64][64]

#define PIX 4224                   // 66*64 u16 per padded row
#define PIMG 244992                // 58*PIX u16 per padded image
#define BIMG ((size_t)8 * PIMG)    // u16 per image set (8 batches)
#define WXS ((size_t)5505024)      // u16 per wx slot: 8*56*64*192
#define HL_OFF ((size_t)25690112)  // 8*16*64*3136 floats
#define SLOTW 4224                 // u16 per full-width ring slot (66px x 64ci)

typedef unsigned short u16;
typedef __attribute__((ext_vector_type(8))) __bf16 bf16x8;
typedef __attribute__((ext_vector_type(4))) float f32x4;

__device__ __forceinline__ float bf2f(u16 u) {
  unsigned v = ((unsigned)u) << 16;
  float f;
  __builtin_memcpy(&f, &v, 4);
  return f;
}
__device__ __forceinline__ u16 f2bf(float f) {
  unsigned u;
  __builtin_memcpy(&u, &f, 4);
  u = (u + 0x7FFFu + ((u >> 16) & 1u)) >> 16;  // RNE
  return (u16)u;
}
__device__ __forceinline__ void gll16(const u16* g, u16* l) {
  __builtin_amdgcn_global_load_lds(
      (const __attribute__((address_space(1))) void*)g,
      (__attribute__((address_space(3))) void*)l, 16, 0, 0);
}

// ---- stage one FULL padded row (66px x 64ci = 8448B) into ring slot ---------
__device__ __forceinline__ void stage_rowf(const u16* img, int prow, u16* ring,
                                           int slot, int lane, int wv) {
  const u16* g = img + (size_t)prow * PIX;
  u16* l = ring + slot * SLOTW;
#pragma unroll
  for (int c = wv; c < 8; c += 4) gll16(g + c * 512 + lane * 8, l + c * 512);
  if (wv == 3 && lane < 16) gll16(g + 4096 + lane * 8, l + 4096);
}

// ---- full-K weight fragments for one 32ch slice: 36 x bf16x8 (144 VGPR) ----
__device__ __forceinline__ void loadB36(const u16* wr, int NCH,
                                        bf16x8 (&B)[6][3][2]) {
#pragma unroll
  for (int p = 0; p < 6; ++p) {
    const int ky = p >> 1, kc = p & 1;
#pragma unroll
    for (int kx = 0; kx < 3; ++kx)
#pragma unroll
      for (int nf = 0; nf < 2; ++nf)
        B[p][kx][nf] = *(const bf16x8*)(wr + (size_t)((ky * 3 + kx) * NCH) * 64 +
                                        nf * 1024 + kc * 32);
  }
}

// ---- one output row: 32px x 32ch per wave, K=576 (72 MFMA, 36 ds_read) -----
__device__ __forceinline__ void conv_unit2(const u16* ring, int rcb,
                                           const bf16x8 (&B)[6][3][2],
                                           f32x4 (&acc)[2][2], int lane,
                                           int x0w) {
#pragma unroll
  for (int p = 0; p < 6; ++p) {
    const int ky = p >> 1, kc = p & 1;
    const int slot = (rcb + ky) & 3;
    bf16x8 af[2][3];
#pragma unroll
    for (int mf = 0; mf < 2; ++mf)
#pragma unroll
      for (int kx = 0; kx < 3; ++kx) {
        const int pp = x0w + mf * 16 + (lane & 15) + kx;
        const int sl = (kc * 4 + (lane >> 4)) ^ (pp & 7);
        af[mf][kx] = *(const bf16x8*)(ring + slot * SLOTW + pp * 64 + sl * 8);
      }
#pragma unroll
    for (int kx = 0; kx < 3; ++kx)
#pragma unroll
      for (int mf = 0; mf < 2; ++mf)
#pragma unroll
        for (int nf = 0; nf < 2; ++nf)
          acc[mf][nf] = __builtin_amdgcn_mfma_f32_16x16x32_bf16(
              af[mf][kx], B[p][kx][nf], acc[mf][nf], 0, 0, 0);
  }
}

#define UNIT_SYNC() \
  asm volatile("s_waitcnt vmcnt(0)" ::: "memory"); \
  __syncthreads();

// ---- convW role: id in [0,168): ns(3) x b(8) x v(7), 8 y-units -------------
__device__ __forceinline__ void do_convW(const u16* __restrict__ xslot,
                                         const u16* __restrict__ wcat,
                                         u16* __restrict__ wx, int id,
                                         u16* ring) {
  const int ns = id / 56;
  const int rem = id % 56;
  const int b = rem & 7;
  const int y0 = (rem >> 3) * 8;  // 0..48
  const int lane = threadIdx.x & 63, wv = threadIdx.x >> 6;
  const int chs = wv & 1, x0w = (wv >> 1) * 32;
  const int nb = ns * 64 + chs * 32;

  const u16* wr = wcat + (size_t)(nb + (lane & 15)) * 64 + (lane >> 4) * 8;
  bf16x8 B[6][3][2];
  loadB36(wr, 192, B);

  const u16* img = xslot + (size_t)b * PIMG;
#pragma unroll
  for (int k = 0; k < 3; ++k) stage_rowf(img, y0 + k, ring, k, lane, wv);

#pragma unroll
  for (int u = 0; u < 8; ++u) {
    UNIT_SYNC();
    if (u < 7) stage_rowf(img, y0 + u + 3, ring, (u + 3) & 3, lane, wv);

    f32x4 acc[2][2];
#pragma unroll
    for (int mf = 0; mf < 2; ++mf)
#pragma unroll
      for (int nf = 0; nf < 2; ++nf) acc[mf][nf] = (f32x4){0.f, 0.f, 0.f, 0.f};
    conv_unit2(ring, u, B, acc, lane, x0w);

    const int y = y0 + u;
    const size_t rowb = ((size_t)(b * 56) + y) * 64;
#pragma unroll
    for (int mf = 0; mf < 2; ++mf)
#pragma unroll
      for (int nf = 0; nf < 2; ++nf) {
        const int n = nb + nf * 16 + (lane & 15);
#pragma unroll
        for (int r = 0; r < 4; ++r) {
          const int px = x0w + mf * 16 + 4 * (lane >> 4) + r;
          wx[(rowb + px) * 192 + n] = f2bf(acc[mf][nf][r]);
        }
      }
  }
}

// ---- xprep row: NCHW f32 -> padded bf16 slot (swizzled) --------------------
__device__ __forceinline__ void xprep_row(const float* __restrict__ x,
                                          u16* __restrict__ dst, int t, int b,
                                          int y, float (*tx)[57]) {
  const int tid = threadIdx.x;
  for (int i = tid; i < 64 * 56; i += 256) {
    int ci = i / 56, px = i % 56;
    tx[ci][px] = x[((size_t)(b * 16 + t) * 64 + ci) * 3136 + y * 56 + px];
  }
  __syncthreads();
  const size_t pb = (size_t)b * PIMG + (size_t)(y + 1) * PIX;
  for (int i = tid; i < 56 * 64; i += 256) {
    int px = i / 64, ci = i % 64;
    int gx = px + 1;
    dst[pb + gx * 64 + (((ci >> 3) ^ (gx & 7)) << 3) + (ci & 7)] =
        f2bf(tx[ci][px]);
  }
}

// ---- prep kernels -----------------------------------------------------------
__global__ __launch_bounds__(256) void wprep_k(const float* __restrict__ W,
                                               const float* __restrict__ U,
                                               const float* __restrict__ C,
                                               u16* __restrict__ wcat) {
  int i = blockIdx.x * 256 + threadIdx.x;
  if (i >= 221184) return;
  float v;
  if (i < 110592) {  // W: [9][192][64]
    int plane = i / 12288, rem = i % 12288, o = rem / 64, ci = rem % 64;
    v = W[(size_t)(o * 64 + ci) * 9 + plane];
  } else if (i < 184320) {  // U: [9][128][64]
    int j = i - 110592;
    int plane = j / 8192, rem = j % 8192, o = rem / 64, ci = rem % 64;
    v = U[(size_t)(o * 64 + ci) * 9 + plane];
  } else {  // C: [9][64][64]
    int j = i - 184320;
    int plane = j / 4096, rem = j % 4096, o = rem / 64, ci = rem % 64;
    v = C[(size_t)(o * 64 + ci) * 9 + plane];
  }
  wcat[i] = f2bf(v);
}

__global__ __launch_bounds__(256) void hinit_k(const float* __restrict__ h,
                                               u16* __restrict__ hpad,
                                               _Float16* __restrict__ hstate) {
  __shared__ float t[64][57];
  const int y = blockIdx.x, b = blockIdx.y;
  const int tid = threadIdx.x;
  for (int i = tid; i < 64 * 56; i += 256) {
    int ci = i / 56, xx = i % 56;
    t[ci][xx] = h[((size_t)(b * 64) + ci) * 3136 + y * 56 + xx];
  }
  __syncthreads();
  const size_t pb = (size_t)b * PIMG + (size_t)(y + 1) * PIX;
  const size_t sb = ((size_t)(b * 56) + y) * 64;
  for (int i = tid; i < 56 * 64; i += 256) {
    int px = i / 64, ci = i % 64;
    float v = t[ci][px];
    int gx = px + 1;
    hpad[pb + gx * 64 + (((ci >> 3) ^ (gx & 7)) << 3) + (ci & 7)] = f2bf(v);
    hstate[(sb + px) * 64 + ci] = (_Float16)v;
  }
}

__global__ __launch_bounds__(256) void xprep01_k(const float* __restrict__ x,
                                                 u16* __restrict__ x0,
                                                 u16* __restrict__ x1) {
  __shared__ float tt[64][57];
  const int t = blockIdx.y;
  xprep_row(x, t ? x1 : x0, t, blockIdx.x & 7, blockIdx.x >> 3, tt);
}

__global__ __launch_bounds__(256, 2) void convW0_k(const u16* __restrict__ xs,
                                                   const u16* __restrict__ wcat,
                                                   u16* __restrict__ wx) {
  __shared__ __align__(16) u16 ring[4 * SLOTW];
  do_convW(xs, wcat, wx, blockIdx.x, ring);
}

// ---- convUW: convU(t) [bid<224] || convW(t+1) [bid>=224] --------------------
__global__ __launch_bounds__(256, 2) void convUW_k(
    const u16* __restrict__ hpad, const u16* __restrict__ xpad_n,
    const u16* __restrict__ wcat, const u16* __restrict__ wx_c,
    u16* __restrict__ wx_n, _Float16* __restrict__ zbuf,
    u16* __restrict__ rhpad) {
  __shared__ __align__(16) u16 ring[4 * SLOTW];
  const int bid = blockIdx.x;
  if (bid >= 224) {
    do_convW(xpad_n, wcat, wx_n, bid - 224, ring);
    return;
  }
  const int ns = bid / 112;  // 0: z-gate, 1: r-gate
  const int rem = bid % 112;
  const int b = rem & 7;
  const int y0 = (rem >> 3) * 4;  // 0..52
  const int lane = threadIdx.x & 63, wv = threadIdx.x >> 6;
  const int chs = wv & 1, x0w = (wv >> 1) * 32;
  const int nb = ns * 64 + chs * 32;  // U-channel base (z:0..63, r:64..127)

  const u16* wr =
      wcat + 110592 + (size_t)(nb + (lane & 15)) * 64 + (lane >> 4) * 8;
  bf16x8 B[6][3][2];
  loadB36(wr, 128, B);

  const u16* img = hpad + (size_t)b * PIMG;
#pragma unroll
  for (int k = 0; k < 3; ++k) stage_rowf(img, y0 + k, ring, k, lane, wv);

#pragma unroll
  for (int u = 0; u < 4; ++u) {
    UNIT_SYNC();
    if (u < 3) stage_rowf(img, y0 + u + 3, ring, (u + 3) & 3, lane, wv);

    f32x4 acc[2][2];
#pragma unroll
    for (int mf = 0; mf < 2; ++mf)
#pragma unroll
      for (int nf = 0; nf < 2; ++nf) acc[mf][nf] = (f32x4){0.f, 0.f, 0.f, 0.f};
    conv_unit2(ring, u, B, acc, lane, x0w);

    const int y = y0 + u;
    const size_t rowb = ((size_t)(b * 56) + y) * 64;
#pragma unroll
    for (int mf = 0; mf < 2; ++mf)
#pragma unroll
      for (int nf = 0; nf < 2; ++nf) {
        const int n = nb + nf * 16 + (lane & 15);           // wx channel
        const int cl = chs * 32 + nf * 16 + (lane & 15);    // 0..63
#pragma unroll
        for (int r = 0; r < 4; ++r) {
          const int px = x0w + mf * 16 + 4 * (lane >> 4) + r;
          if (px < 56) {
            const float a = bf2f(wx_c[(rowb + px) * 192 + n]) + acc[mf][nf][r];
            const float s = 1.f / (1.f + __expf(-a));
            if (ns == 0) {
              zbuf[(rowb + px) * 64 + cl] = (_Float16)s;
            } else {
              const int cp = px + 1;           // padded center col
              const int slotc = (u + 1) & 3;   // center row in ring
              const float hv =
                  bf2f(ring[slotc * SLOTW + cp * 64 +
                            (((cl >> 3) ^ (cp & 7)) << 3) + (cl & 7)]);
              rhpad[(size_t)b * PIMG + (size_t)(y + 1) * PIX + cp * 64 +
                    (((cl >> 3) ^ (cp & 7)) << 3) + (cl & 7)] = f2bf(s * hv);
            }
          }
        }
      }
  }
}

// ---- convCX: convC(t) [bid<112] || xprep(t+2) [bid>=112] --------------------
__global__ __launch_bounds__(256, 2) void convCX_k(
    const float* __restrict__ x, u16* __restrict__ xpad_w,
    const u16* __restrict__ rhpad, const u16* __restrict__ wcat,
    const u16* __restrict__ wx_c, const _Float16* __restrict__ zbuf,
    _Float16* __restrict__ hstate, u16* __restrict__ hpad,
    float* __restrict__ out, int t) {
  __shared__ __align__(16) u16 ring[4 * SLOTW];
  __shared__ float ldt[4][32][33];
  const int bid = blockIdx.x;
  if (bid >= 112) {
    const int id = bid - 112;
    xprep_row(x, xpad_w, t + 2, id & 7, id >> 3, (float(*)[57])ring);
    return;
  }
  const int b = bid & 7;
  const int y0 = (bid >> 3) * 4;  // 0..52
  const int lane = threadIdx.x & 63, wv = threadIdx.x >> 6;
  const int chs = wv & 1, x0w = (wv >> 1) * 32;
  const int nb = chs * 32;

  const u16* wr =
      wcat + 184320 + (size_t)(nb + (lane & 15)) * 64 + (lane >> 4) * 8;
  bf16x8 B[6][3][2];
  loadB36(wr, 64, B);

  const u16* img = rhpad + (size_t)b * PIMG;
#pragma unroll
  for (int k = 0; k < 3; ++k) stage_rowf(img, y0 + k, ring, k, lane, wv);

#pragma unroll
  for (int u = 0; u < 4; ++u) {
    UNIT_SYNC();
    if (u < 3) stage_rowf(img, y0 + u + 3, ring, (u + 3) & 3, lane, wv);

    f32x4 acc[2][2];
#pragma unroll
    for (int mf = 0; mf < 2; ++mf)
#pragma unroll
      for (int nf = 0; nf < 2; ++nf) acc[mf][nf] = (f32x4){0.f, 0.f, 0.f, 0.f};
    conv_unit2(ring, u, B, acc, lane, x0w);

    const int y = y0 + u;
    const size_t rowb = ((size_t)(b * 56) + y) * 64;
    float hnv[2][2][4];
#pragma unroll
    for (int mf = 0; mf < 2; ++mf)
#pragma unroll
      for (int nf = 0; nf < 2; ++nf) {
        const int n = nb + nf * 16 + (lane & 15);
#pragma unroll
        for (int r = 0; r < 4; ++r) {
          const int px = x0w + mf * 16 + 4 * (lane >> 4) + r;
          hnv[mf][nf][r] = 0.f;
          if (px < 56) {
            const float a =
                bf2f(wx_c[(rowb + px) * 192 + 128 + n]) + acc[mf][nf][r];
            const float htil = tanhf(a);
            const float z = (float)zbuf[(rowb + px) * 64 + n];
            const float ho = (float)hstate[(rowb + px) * 64 + n];
            const float hn = fmaf(z, htil - ho, ho);
            hstate[(rowb + px) * 64 + n] = (_Float16)hn;
            const int gx = px + 1;
            hpad[(size_t)b * PIMG + (size_t)(y + 1) * PIX + gx * 64 +
                 (((n >> 3) ^ (gx & 7)) << 3) + (n & 7)] = f2bf(hn);
            hnv[mf][nf][r] = hn;
          }
        }
      }
    __syncthreads();
#pragma unroll
    for (int mf = 0; mf < 2; ++mf)
#pragma unroll
      for (int nf = 0; nf < 2; ++nf)
#pragma unroll
        for (int r = 0; r < 4; ++r)
          ldt[wv][nf * 16 + (lane & 15)][mf * 16 + 4 * (lane >> 4) + r] =
              hnv[mf][nf][r];
    __syncthreads();
    const int xl = lane & 31;
    const int px = x0w + xl;
    if (px < 56) {
#pragma unroll
      for (int cc = 0; cc < 16; ++cc) {
        const int ch = (lane >> 5) * 16 + cc;
        const float v = ldt[wv][ch][xl];
        const int oc = nb + ch;
        out[(((size_t)(b * 16 + t)) * 64 + oc) * 3136 + y * 56 + px] = v;
        if (t == 15)
          out[HL_OFF + ((size_t)(b * 64) + oc) * 3136 + y * 56 + px] = v;
      }
    }
  }
}

extern "C" void kernel_launch(void* const* d_in, const int* in_sizes, int n_in,
                              void* d_out, int out_size, void* d_ws,
                              size_t ws_size, hipStream_t stream) {
  const float* x = (const float*)d_in[0];
  const float* h = (const float*)d_in[1];
  const float* W = (const float*)d_in[2];
  const float* U = (const float*)d_in[3];
  const float* C = (const float*)d_in[4];
  float* out = (float*)d_out;

  u16* ws_u = (u16*)d_ws;
  u16* xpad = ws_u;                             // 2 slots x BIMG
  u16* hpad = xpad + 2 * BIMG;                  // BIMG
  u16* rhpad = hpad + BIMG;                     // BIMG
  u16* wcat = rhpad + BIMG;                     // 221,184
  u16* wxr = wcat + 221184;                     // 2 slots x WXS
  _Float16* zbuf = (_Float16*)(wxr + 2 * WXS);  // 1,835,008 fp16
  _Float16* hstate = zbuf + 1835008;            // 1,835,008 fp16

  // zero the 4 padded images (borders must stay 0)
  hipMemsetAsync(d_ws, 0, (size_t)4 * BIMG * sizeof(u16), stream);
  wprep_k<<<864, 256, 0, stream>>>(W, U, C, wcat);
  hinit_k<<<dim3(56, 8), 256, 0, stream>>>(h, hpad, hstate);
  xprep01_k<<<dim3(448, 2), 256, 0, stream>>>(x, xpad, xpad + BIMG);
  convW0_k<<<168, 256, 0, stream>>>(xpad, wcat, wxr);  // wx(0) -> slot 0

  for (int t = 0; t < 16; ++t) {
    u16* xn = xpad + (size_t)((t + 1) & 1) * BIMG;  // x(t+1) image
    u16* xw = xpad + (size_t)(t & 1) * BIMG;        // xprep(t+2) target
    const u16* wxc = wxr + (size_t)(t & 1) * WXS;   // wx(t)
    u16* wxn = wxr + (size_t)((t + 1) & 1) * WXS;   // wx(t+1)

    const int nbA = 224 + ((t < 15) ? 168 : 0);
    convUW_k<<<nbA, 256, 0, stream>>>(hpad, xn, wcat, wxc, wxn, zbuf, rhpad);

    const int nbB = 112 + ((t < 14) ? 448 : 0);
    convCX_k<<<nbB, 256, 0, stream>>>(x, xw, rhpad, wcat, wxc, zbuf, hstate,
                                      hpad, out, t);
  }
}

// Round 13
// 830.008 us; speedup vs baseline: 1.7038x; 1.7038x over previous
//
#include <hip/hip_runtime.h>
#include <math.h>

// GRU-RCN bf16 MFMA, round-13: r11 structure (814us baseline) + vectorized
// epilogues (LDS repack -> 16B coalesced stores) + balanced convW riders.
// B=8,T=16,C=Oh=64,HxW=56x56, 3x3 SAME.
// Per step t:
//   convUW: blocks<448 convU(t) -> z, r*h ; blocks>=448 convW(t+1) [672 riders]
//   convCX: blocks<448 convC(t) -> h', out ; blocks>=448 xprep(t+2)
// Layouts:
//   padded imgs (xpad[2]/hpad/rhpad): bf16 [b][58][66][64ci], 16B ci-slices
//     XOR-swizzled by (col&7) -> conflict-free ds_read_b128.
//   wcat: bf16 [plane(ky*3+kx)][o][ci] (W:192, U:128, C:64)
//   wx[2]: bf16 [b][y56][px64][192]; zbuf/hstate: fp16 [b][y][px64][64]

#define PIX 4224                   // 66*64 u16 per padded row
#define PIMG 244992                // 58*PIX u16 per padded image
#define BIMG ((size_t)8 * PIMG)    // u16 per image set (8 batches)
#define WXS ((size_t)5505024)      // u16 per wx slot: 8*56*64*192
#define HL_OFF ((size_t)25690112)  // 8*16*64*3136 floats
#define SLOT 2176                  // u16 per ring row slot (34px x 64ci)

typedef unsigned short u16;
typedef __attribute__((ext_vector_type(8))) __bf16 bf16x8;
typedef __attribute__((ext_vector_type(4))) float f32x4;
typedef __attribute__((ext_vector_type(4))) unsigned int u32x4;

__device__ __forceinline__ float bf2f(u16 u) {
  unsigned v = ((unsigned)u) << 16;
  float f;
  __builtin_memcpy(&f, &v, 4);
  return f;
}
__device__ __forceinline__ u16 f2bf(float f) {
  unsigned u;
  __builtin_memcpy(&u, &f, 4);
  u = (u + 0x7FFFu + ((u >> 16) & 1u)) >> 16;  // RNE
  return (u16)u;
}
__device__ __forceinline__ u16 f2h(float f) {
  _Float16 h = (_Float16)f;
  u16 u;
  __builtin_memcpy(&u, &h, 2);
  return u;
}
__device__ __forceinline__ void gll16(const u16* g, u16* l) {
  __builtin_amdgcn_global_load_lds(
      (const __attribute__((address_space(1))) void*)g,
      (__attribute__((address_space(3))) void*)l, 16, 0, 0);
}

// ---- stage one padded row (34px x 64ci = 4352B) into ring slot --------------
__device__ __forceinline__ void stage_row(const u16* img, int prow, int x0,
                                          u16* ring, int slot, int lane,
                                          int wv) {
  const u16* g = img + (size_t)prow * PIX + x0 * 64;
  u16* l = ring + slot * SLOT;
  gll16(g + wv * 512 + lane * 8, l + wv * 512);
  if (wv == 0 && lane < 16) gll16(g + 2048 + lane * 8, l + 2048);
}

// ---- full-K weight fragments for one 16ch slice: 18 x bf16x8 ---------------
__device__ __forceinline__ void loadB18(const u16* wr, int NCH,
                                        bf16x8 (&B)[6][3]) {
#pragma unroll
  for (int p = 0; p < 6; ++p) {
    const int ky = p >> 1, kc = p & 1;
#pragma unroll
    for (int kx = 0; kx < 3; ++kx)
      B[p][kx] = *(const bf16x8*)(wr + (size_t)((ky * 3 + kx) * NCH) * 64 +
                                  kc * 32);
  }
}

// ---- one output row: 32px x 16ch, K=576 (36 MFMA) --------------------------
__device__ __forceinline__ void conv_unit(const u16* ring, int rcb,
                                          const bf16x8 (&B)[6][3],
                                          f32x4 (&acc)[2], int lane) {
#pragma unroll
  for (int p = 0; p < 6; ++p) {
    const int ky = p >> 1, kc = p & 1;
    const int slot = (rcb + ky) & 7;
    bf16x8 af[2][3];
#pragma unroll
    for (int mf = 0; mf < 2; ++mf)
#pragma unroll
      for (int kx = 0; kx < 3; ++kx) {
        const int pp = mf * 16 + (lane & 15) + kx;
        const int sl = (kc * 4 + (lane >> 4)) ^ (pp & 7);
        af[mf][kx] = *(const bf16x8*)(ring + slot * SLOT + pp * 64 + sl * 8);
      }
#pragma unroll
    for (int kx = 0; kx < 3; ++kx)
#pragma unroll
      for (int mf = 0; mf < 2; ++mf)
        acc[mf] = __builtin_amdgcn_mfma_f32_16x16x32_bf16(af[mf][kx], B[p][kx],
                                                          acc[mf], 0, 0, 0);
  }
}

#define UNIT_SYNC() \
  asm volatile("s_waitcnt vmcnt(0)" ::: "memory"); \
  __syncthreads();

// ---- convW role: id in [0,672) = ns(3) x b(8) x x(2) x yq(14); 4 y-units ---
__device__ __forceinline__ void do_convW(const u16* __restrict__ xslot,
                                         const u16* __restrict__ wcat,
                                         u16* __restrict__ wx, int id,
                                         u16* ring, u16* tile) {
  const int ns = id / 224;
  const int rem = id % 224;
  const int b = rem & 7;
  const int v = rem >> 3;       // 0..27
  const int x0 = (v & 1) * 32;
  const int y0 = (v >> 1) * 4;  // 0..52
  const int lane = threadIdx.x & 63, wv = threadIdx.x >> 6;
  const int nl = wv * 16 + (lane & 15);  // 0..63 block-local channel

  const u16* wr =
      wcat + (size_t)(ns * 64 + nl) * 64 + (lane >> 4) * 8;
  bf16x8 B[6][3];
  loadB18(wr, 192, B);

  const u16* img = xslot + (size_t)b * PIMG;
#pragma unroll
  for (int k = 0; k < 3; ++k) stage_row(img, y0 + k, x0, ring, k, lane, wv);

#pragma unroll
  for (int u = 0; u < 4; ++u) {
    UNIT_SYNC();
    if (u < 3) stage_row(img, y0 + u + 3, x0, ring, (u + 3) & 7, lane, wv);

    f32x4 acc[2] = {{0.f, 0.f, 0.f, 0.f}, {0.f, 0.f, 0.f, 0.f}};
    conv_unit(ring, u, B, acc, lane);

    const int y = y0 + u;
    const size_t rowb = ((size_t)(b * 56) + y) * 64;
#pragma unroll
    for (int mf = 0; mf < 2; ++mf)
#pragma unroll
      for (int r = 0; r < 4; ++r) {
        const int pl = mf * 16 + 4 * (lane >> 4) + r;
        tile[pl * 64 + nl] = f2bf(acc[mf][r]);
      }
    __syncthreads();
    {
      const int c = threadIdx.x, pl = c >> 3, off = c & 7;
      *(u32x4*)(wx + (rowb + x0 + pl) * 192 + ns * 64 + off * 8) =
          *(const u32x4*)(tile + pl * 64 + off * 8);
    }
  }
}

// ---- xprep row: NCHW f32 -> padded bf16 slot (swizzled) --------------------
__device__ __forceinline__ void xprep_row(const float* __restrict__ x,
                                          u16* __restrict__ dst, int t, int b,
                                          int y, float (*tx)[57]) {
  const int tid = threadIdx.x;
  for (int i = tid; i < 64 * 56; i += 256) {
    int ci = i / 56, px = i % 56;
    tx[ci][px] = x[((size_t)(b * 16 + t) * 64 + ci) * 3136 + y * 56 + px];
  }
  __syncthreads();
  const size_t pb = (size_t)b * PIMG + (size_t)(y + 1) * PIX;
  for (int i = tid; i < 56 * 64; i += 256) {
    int px = i / 64, ci = i % 64;
    int gx = px + 1;
    dst[pb + gx * 64 + (((ci >> 3) ^ (gx & 7)) << 3) + (ci & 7)] =
        f2bf(tx[ci][px]);
  }
}

// ---- prep kernels -----------------------------------------------------------
__global__ __launch_bounds__(256) void wprep_k(const float* __restrict__ W,
                                               const float* __restrict__ U,
                                               const float* __restrict__ C,
                                               u16* __restrict__ wcat) {
  int i = blockIdx.x * 256 + threadIdx.x;
  if (i >= 221184) return;
  float v;
  if (i < 110592) {  // W: [9][192][64]
    int plane = i / 12288, rem = i % 12288, o = rem / 64, ci = rem % 64;
    v = W[(size_t)(o * 64 + ci) * 9 + plane];
  } else if (i < 184320) {  // U: [9][128][64]
    int j = i - 110592;
    int plane = j / 8192, rem = j % 8192, o = rem / 64, ci = rem % 64;
    v = U[(size_t)(o * 64 + ci) * 9 + plane];
  } else {  // C: [9][64][64]
    int j = i - 184320;
    int plane = j / 4096, rem = j % 4096, o = rem / 64, ci = rem % 64;
    v = C[(size_t)(o * 64 + ci) * 9 + plane];
  }
  wcat[i] = f2bf(v);
}

__global__ __launch_bounds__(256) void hinit_k(const float* __restrict__ h,
                                               u16* __restrict__ hpad,
                                               _Float16* __restrict__ hstate) {
  __shared__ float t[64][57];
  const int y = blockIdx.x, b = blockIdx.y;
  const int tid = threadIdx.x;
  for (int i = tid; i < 64 * 56; i += 256) {
    int ci = i / 56, xx = i % 56;
    t[ci][xx] = h[((size_t)(b * 64) + ci) * 3136 + y * 56 + xx];
  }
  __syncthreads();
  const size_t pb = (size_t)b * PIMG + (size_t)(y + 1) * PIX;
  const size_t sb = ((size_t)(b * 56) + y) * 64;
  for (int i = tid; i < 56 * 64; i += 256) {
    int px = i / 64, ci = i % 64;
    float v = t[ci][px];
    int gx = px + 1;
    hpad[pb + gx * 64 + (((ci >> 3) ^ (gx & 7)) << 3) + (ci & 7)] = f2bf(v);
    hstate[(sb + px) * 64 + ci] = (_Float16)v;
  }
}

__global__ __launch_bounds__(256) void xprep01_k(const float* __restrict__ x,
                                                 u16* __restrict__ x0,
                                                 u16* __restrict__ x1) {
  __shared__ float tt[64][57];
  const int t = blockIdx.y;
  xprep_row(x, t ? x1 : x0, t, blockIdx.x & 7, blockIdx.x >> 3, tt);
}

__global__ __launch_bounds__(256, 3) void convW0_k(const u16* __restrict__ xs,
                                                   const u16* __restrict__ wcat,
                                                   u16* __restrict__ wx) {
  __shared__ __align__(16) u16 ring[8 * SLOT];
  __shared__ __align__(16) u16 tile[32 * 64];
  do_convW(xs, wcat, wx, blockIdx.x, ring, tile);
}

// ---- convUW: convU(t) [bid<448] || convW(t+1) [bid>=448, 672 riders] -------
__global__ __launch_bounds__(256, 3) void convUW_k(
    const u16* __restrict__ hpad, const u16* __restrict__ xpad_n,
    const u16* __restrict__ wcat, const u16* __restrict__ wx_c,
    u16* __restrict__ wx_n, _Float16* __restrict__ zbuf,
    u16* __restrict__ rhpad) {
  __shared__ __align__(16) u16 ring[8 * SLOT];
  __shared__ __align__(16) u16 tile[32 * 64];
  const int bid = blockIdx.x;
  if (bid >= 448) {
    do_convW(xpad_n, wcat, wx_n, bid - 448, ring, tile);
    return;
  }
  const int ns = bid / 224;  // 0: z-gate, 1: r-gate
  const int rem = bid % 224;
  const int b = rem & 7;
  const int r2 = rem >> 3;
  const int x0 = (r2 & 1) * 32;
  const int y0 = (r2 >> 1) * 4;
  const int lane = threadIdx.x & 63, wv = threadIdx.x >> 6;
  const int nl = wv * 16 + (lane & 15);  // 0..63 within gate
  const int n = ns * 64 + nl;            // U channel / wx channel

  const u16* wr =
      wcat + 110592 + (size_t)n * 64 + (lane >> 4) * 8;
  bf16x8 B[6][3];
  loadB18(wr, 128, B);

  const u16* img = hpad + (size_t)b * PIMG;
#pragma unroll
  for (int k = 0; k < 3; ++k) stage_row(img, y0 + k, x0, ring, k, lane, wv);

#pragma unroll
  for (int u = 0; u < 4; ++u) {
    UNIT_SYNC();
    if (u < 3) stage_row(img, y0 + u + 3, x0, ring, (u + 3) & 7, lane, wv);

    f32x4 acc[2] = {{0.f, 0.f, 0.f, 0.f}, {0.f, 0.f, 0.f, 0.f}};
    conv_unit(ring, u, B, acc, lane);

    const int y = y0 + u;
    const size_t rowb = ((size_t)(b * 56) + y) * 64;
#pragma unroll
    for (int mf = 0; mf < 2; ++mf)
#pragma unroll
      for (int r = 0; r < 4; ++r) {
        const int pl = mf * 16 + 4 * (lane >> 4) + r;
        const int pg = x0 + pl;
        const float a = bf2f(wx_c[(rowb + pg) * 192 + n]) + acc[mf][r];
        const float s = 1.f / (1.f + __expf(-a));
        if (ns == 0) {
          tile[pl * 64 + nl] = f2h(s);
        } else {
          const int cp = pl + 1;  // strip-local center col
          const int sw = (((nl >> 3) ^ (cp & 7)) << 3) | (nl & 7);
          const float hv = bf2f(ring[((u + 1) & 7) * SLOT + cp * 64 + sw]);
          tile[pl * 64 + sw] = f2bf((pg < 56) ? s * hv : 0.f);
        }
      }
    __syncthreads();
    {
      const int c = threadIdx.x, pl = c >> 3, off = c & 7;
      const u32x4 vv = *(const u32x4*)(tile + pl * 64 + off * 8);
      if (ns == 0)
        *(u32x4*)((u16*)zbuf + (rowb + x0 + pl) * 64 + off * 8) = vv;
      else
        *(u32x4*)(rhpad + (size_t)b * PIMG + (size_t)(y + 1) * PIX +
                  (x0 + pl + 1) * 64 + off * 8) = vv;
    }
  }
}

// ---- convCX: convC(t) [bid<448] || xprep(t+2) [bid>=448] --------------------
__global__ __launch_bounds__(256, 3) void convCX_k(
    const float* __restrict__ x, u16* __restrict__ xpad_w,
    const u16* __restrict__ rhpad, const u16* __restrict__ wcat,
    const u16* __restrict__ wx_c, const _Float16* __restrict__ zbuf,
    _Float16* __restrict__ hstate, u16* __restrict__ hpad,
    float* __restrict__ out, int t) {
  __shared__ __align__(16) u16 ring[8 * SLOT];
  __shared__ float ldt[4][16][33];
  __shared__ __align__(16) u16 th[32 * 64];
  __shared__ __align__(16) u16 tp[32 * 64];
  const int bid = blockIdx.x;
  if (bid >= 448) {
    const int id = bid - 448;
    xprep_row(x, xpad_w, t + 2, id & 7, id >> 3, (float(*)[57])ring);
    return;
  }
  const int b = bid & 7;
  const int r2 = bid >> 3;       // 0..55
  const int x0 = (r2 & 1) * 32;
  const int y0 = (r2 >> 1) * 2;  // 0..54
  const int lane = threadIdx.x & 63, wv = threadIdx.x >> 6;
  const int nl = wv * 16 + (lane & 15);  // 0..63

  const u16* wr =
      wcat + 184320 + (size_t)nl * 64 + (lane >> 4) * 8;
  bf16x8 B[6][3];
  loadB18(wr, 64, B);

  const u16* img = rhpad + (size_t)b * PIMG;
#pragma unroll
  for (int k = 0; k < 3; ++k) stage_row(img, y0 + k, x0, ring, k, lane, wv);

#pragma unroll
  for (int u = 0; u < 2; ++u) {
    UNIT_SYNC();
    if (u == 0) stage_row(img, y0 + 3, x0, ring, 3, lane, wv);

    f32x4 acc[2] = {{0.f, 0.f, 0.f, 0.f}, {0.f, 0.f, 0.f, 0.f}};
    conv_unit(ring, u, B, acc, lane);

    const int y = y0 + u;
    const size_t rowb = ((size_t)(b * 56) + y) * 64;
#pragma unroll
    for (int mf = 0; mf < 2; ++mf)
#pragma unroll
      for (int r = 0; r < 4; ++r) {
        const int pl = mf * 16 + 4 * (lane >> 4) + r;
        const int pg = x0 + pl;
        const float a = bf2f(wx_c[(rowb + pg) * 192 + 128 + nl]) + acc[mf][r];
        const float htil = tanhf(a);
        const float z = (float)zbuf[(rowb + pg) * 64 + nl];
        const float ho = (float)hstate[(rowb + pg) * 64 + nl];
        float hn = fmaf(z, htil - ho, ho);
        hn = (pg < 56) ? hn : 0.f;
        th[pl * 64 + nl] = f2h(hn);
        const int cp = pl + 1;
        tp[pl * 64 + ((((nl >> 3) ^ (cp & 7)) << 3) | (nl & 7))] = f2bf(hn);
        ldt[wv][lane & 15][pl] = hn;
      }
    __syncthreads();
    {
      const int c = threadIdx.x, pl = c >> 3, off = c & 7;
      *(u32x4*)((u16*)hstate + (rowb + x0 + pl) * 64 + off * 8) =
          *(const u32x4*)(th + pl * 64 + off * 8);
      *(u32x4*)(hpad + (size_t)b * PIMG + (size_t)(y + 1) * PIX +
                (x0 + pl + 1) * 64 + off * 8) =
          *(const u32x4*)(tp + pl * 64 + off * 8);
    }
    // out (NCHW) from wave-private ldt slice
    const int xl = lane & 31;
    const int px = x0 + xl;
    if (px < 56) {
#pragma unroll
      for (int cc = 0; cc < 8; ++cc) {
        const int ch = (lane >> 5) * 8 + cc;
        const float v = ldt[wv][ch][xl];
        const int oc = wv * 16 + ch;
        out[(((size_t)(b * 16 + t)) * 64 + oc) * 3136 + y * 56 + px] = v;
        if (t == 15)
          out[HL_OFF + ((size_t)(b * 64) + oc) * 3136 + y * 56 + px] = v;
      }
    }
  }
}

extern "C" void kernel_launch(void* const* d_in, const int* in_sizes, int n_in,
                              void* d_out, int out_size, void* d_ws,
                              size_t ws_size, hipStream_t stream) {
  const float* x = (const float*)d_in[0];
  const float* h = (const float*)d_in[1];
  const float* W = (const float*)d_in[2];
  const float* U = (const float*)d_in[3];
  const float* C = (const float*)d_in[4];
  float* out = (float*)d_out;

  u16* ws_u = (u16*)d_ws;
  u16* xpad = ws_u;                             // 2 slots x BIMG
  u16* hpad = xpad + 2 * BIMG;                  // BIMG
  u16* rhpad = hpad + BIMG;                     // BIMG
  u16* wcat = rhpad + BIMG;                     // 221,184
  u16* wxr = wcat + 221184;                     // 2 slots x WXS
  _Float16* zbuf = (_Float16*)(wxr + 2 * WXS);  // 1,835,008 fp16
  _Float16* hstate = zbuf + 1835008;            // 1,835,008 fp16

  // zero the 4 padded images (borders must stay 0)
  hipMemsetAsync(d_ws, 0, (size_t)4 * BIMG * sizeof(u16), stream);
  wprep_k<<<864, 256, 0, stream>>>(W, U, C, wcat);
  hinit_k<<<dim3(56, 8), 256, 0, stream>>>(h, hpad, hstate);
  xprep01_k<<<dim3(448, 2), 256, 0, stream>>>(x, xpad, xpad + BIMG);
  convW0_k<<<672, 256, 0, stream>>>(xpad, wcat, wxr);  // wx(0) -> slot 0

  for (int t = 0; t < 16; ++t) {
    u16* xn = xpad + (size_t)((t + 1) & 1) * BIMG;  // x(t+1) image
    u16* xw = xpad + (size_t)(t & 1) * BIMG;        // xprep(t+2) target
    const u16* wxc = wxr + (size_t)(t & 1) * WXS;   // wx(t)
    u16* wxn = wxr + (size_t)((t + 1) & 1) * WXS;   // wx(t+1)

    const int nbA = 448 + ((t < 15) ? 672 : 0);
    convUW_k<<<nbA, 256, 0, stream>>>(hpad, xn, wcat, wxc, wxn, zbuf, rhpad);

    const int nbB = 448 + ((t < 14) ? 448 : 0);
    convCX_k<<<nbB, 256, 0, stream>>>(x, xw, rhpad, wcat, wxc, zbuf, hstate,
                                      hpad, out, t);
  }
}